// Round 1
// 144.332 us; speedup vs baseline: 1.0136x; 1.0136x over previous
//
#include <hip/hip_runtime.h>
#include <hip/hip_bf16.h>
#include <stdint.h>

// Problem constants (fixed by setup_inputs)
#define FCB 2            // codebooks
#define BB 16            // batch
#define NN 256           // tokens per (b)
#define EDIM 1024
#define CC 512           // channels per codebook
#define NE 4096          // prototypes per codebook
#define TOKENS (BB*FCB*NN)   // 8192
#define ROWS (FCB*NE)        // 8192 emb rows
#define OUT_LOSS (BB*NN*EDIM)   // 4194304 (also the element count for the mean)
#define OUT_IDX  (OUT_LOSS + 1)
#define MARGIN 0.15f     // rescore margin, v-units (v = z.e/||e|| ~ 22.6*cos); ~24 sigma of bf16 noise

typedef __attribute__((ext_vector_type(8))) short bf16x8;   // MFMA A/B frag (4 VGPRs)
typedef __attribute__((ext_vector_type(4))) float f32x4;    // 16x16 MFMA C/D frag

// monotonic float<->uint mapping for packed argmax
__device__ __forceinline__ unsigned int ford(float v) {
    unsigned int u = __float_as_uint(v);
    return (u & 0x80000000u) ? ~u : (u | 0x80000000u);
}
__device__ __forceinline__ float unford(unsigned int u) {
    unsigned int b = (u & 0x80000000u) ? (u & 0x7fffffffu) : ~u;
    return __uint_as_float(b);
}

// counted waits (inline asm literals; "memory" clobber pins ordering of LDS/global ops)
__device__ __forceinline__ void vm8()   { asm volatile("s_waitcnt vmcnt(8)" ::: "memory"); }
__device__ __forceinline__ void vm4()   { asm volatile("s_waitcnt vmcnt(4)" ::: "memory"); }
__device__ __forceinline__ void vm0()   { asm volatile("s_waitcnt vmcnt(0)" ::: "memory"); }
__device__ __forceinline__ void lgkm0() { asm volatile("s_waitcnt lgkmcnt(0)" ::: "memory"); }

// ---------------------------------------------------------------------------
// ws layout:
//   [0]        norm_sq   8192 f32                   (32 KB)  memset 0, atomic-accumulated
//   [32768]    cand      8192 tok x 64 slots x 2 u32 (4 MB)  top-2 per 64-col group
//   [32768+4M] loss_tok  8192 f32                   (32 KB)
//   [+32KB]    z_hi      2*4096*512 bf16            (8 MB)   fragment-packed
//   [+8MB]     e_hi      2*4096*512 bf16            (8 MB)
// Packed layout: elem = ((f*256 + R)*64 + Q)*128 + m*8 + j
//   (R = 16-row tile, Q = 8-elem k-chunk, m = row-in-tile, j = elem).
//   One 1-KB staging chunk = (R, qb..qb+3) = 16 rows x 32 k; both the
//   global_load_lds staging and ds_read_b128 fragment reads are lane-linear
//   (lane <-> 16 B), conflict-free.  (R3/R5-proven layout.)
// ---------------------------------------------------------------------------

// ---- pack: fp32 -> bf16 hi, fragment-packed; emb blocks also accumulate ----
// per-row norm^2 partials into norm_sq (selection-only precision).
__global__ __launch_bounds__(256) void pack_hi(
    const float* __restrict__ z, const float* __restrict__ emb,
    short* __restrict__ z_hi, short* __restrict__ e_hi,
    float* __restrict__ norm_sq)
{
    __shared__ float red[256];
    int bid = blockIdx.x;
    int tid = threadIdx.x;
    bool is_emb = (bid >= 2048);
    const float* src; short* hi; int RS, FRO, FCO;
    if (!is_emb) { src = z;   hi = z_hi; RS = EDIM; FRO = 0;  FCO = CC; }
    else         { src = emb; hi = e_hi; RS = CC;   FRO = NE; FCO = 0; bid -= 2048; }
    int u = bid * 256 + tid;                  // [0, 524288)
    int m = u & 15;
    int Q = (u >> 4) & 63;
    int R = (u >> 10) & 255;
    int f = u >> 18;
    int row = R * 16 + m;
    const float* s = src + (size_t)(f * FRO + row) * RS + f * FCO + Q * 8;
    float4 v0 = *(const float4*)s;
    float4 v1 = *(const float4*)(s + 4);
    float vv[8] = {v0.x, v0.y, v0.z, v0.w, v1.x, v1.y, v1.z, v1.w};
    bf16x8 h8;
    float ss = 0.f;
    #pragma unroll
    for (int j = 0; j < 8; ++j) {
        __hip_bfloat16 hb = __float2bfloat16(vv[j]);
        h8[j] = *(short*)&hb;
        ss = fmaf(vv[j], vv[j], ss);
    }
    *(bf16x8*)(hi + (size_t)u * 8) = h8;

    if (is_emb) {
        // block covers 16 rows x 128 k-elems; reduce over the 16 Q-threads/row
        red[tid] = ss;
        __syncthreads();
        if (tid < 16) {
            float t = 0.f;
            #pragma unroll
            for (int q = 0; q < 16; ++q) t += red[tid + 16 * q];
            int bf = (bid * 256) >> 18;
            int bR = ((bid * 256) >> 10) & 255;
            atomicAdd(norm_sq + bf * NE + bR * 16 + tid, t);
        }
    }
}

// ---------------------------------------------------------------------------
// 8-phase 256x256 bf16 MFMA GEMM (BK=64) + per-token top-2-per-64col select.
// 8 waves (2M x 4N), wave = 128x64 = 8x4 tiles of 16x16x32, acc[8][4].
// LDS 128 KiB: buf[2] x { A 32K | B 32K }, each split in k-halves (kh0/kh1,
// 16 KiB = 16 R-groups x 4 Q x 1 KiB).  Per K-step t (4 phases):
//   p1: ds_read B(ks0)+A(mi0-3,ks0); stage A-kh1(t+1)          | bar,lgkm,16 MFMA,bar
//   p2: ds_read A(mi4-7,ks0);        stage B-kh1(t+1); vmcnt(8)| bar,lgkm,16 MFMA,bar
//   p3: ds_read B(ks1)+A(mi0-3,ks1); stage A-kh0(t+2)          | bar,lgkm,16 MFMA,bar
//   p4: ds_read A(mi4-7,ks1);        stage B-kh0(t+2); vmcnt(8)| bar,lgkm,16 MFMA,bar
// Stage targets are free-after-last-read (>=1 barrier separation); counted
// vmcnt(8) = 4 stage-instrs (2 half-tiles) in flight across every barrier.
// Reads-after-stage: kh0(t) landed by vmcnt(8)@t-1:p4; kh1(t) by vmcnt(8)@t:p2.
// Tail: t=6 -> vmcnt(4)@p4; t=7 -> vmcnt(0)@p2 (final drain), no stages.
// ---------------------------------------------------------------------------
__global__ __launch_bounds__(512, 2) void gemm_sel(
    const short* __restrict__ zh, const short* __restrict__ eh,
    const float* __restrict__ norm_sq, unsigned int* __restrict__ cand)
{
    __shared__ __attribute__((aligned(128))) char smem[131072];
    const int f  = blockIdx.z;
    const int t0 = blockIdx.y * 256;  // token base within codebook
    const int m0 = blockIdx.x * 256;  // proto base within codebook
    const int tid  = threadIdx.x;
    const int wave = tid >> 6, lane = tid & 63;
    const int wm = wave & 1, wn = wave >> 1;      // wm 0..1 (M), wn 0..3 (N)

    const int cbA = (f * 256 + (t0 >> 4)) * 64;   // chunk base: +R'*64 + Q
    const int cbB = (f * 256 + (m0 >> 4)) * 64;

    f32x4 acc[8][4] = {};

    // ---- stage one k-half-tile: 2 x global_load_lds(16B) per wave ---------
    auto stage_half = [&](const short* __restrict__ gsrc, int chunk0, char* dst) {
        #pragma unroll
        for (int i = 0; i < 2; ++i) {
            int Rp = wave * 2 + i;
            const short* g = gsrc + ((size_t)(chunk0 + Rp * 64)) * 128 + (size_t)lane * 8;
            __builtin_amdgcn_global_load_lds(
                (const __attribute__((address_space(1))) void*)g,
                (__attribute__((address_space(3))) void*)(dst + Rp * 1024), 16, 0, 0);
        }
    };

    // ---- prologue: kh0(0), kh1(0), kh0(1); keep newest 4 stages in flight -
    stage_half(zh, cbA + 0,     smem + 0);                     // A kh0(0)
    stage_half(eh, cbB + 0,     smem + 32768);                 // B kh0(0)
    stage_half(zh, cbA + 4,     smem + 16384);                 // A kh1(0)
    stage_half(eh, cbB + 4,     smem + 32768 + 16384);         // B kh1(0)
    stage_half(zh, cbA + 8,     smem + 65536);                 // A kh0(1)
    stage_half(eh, cbB + 8,     smem + 65536 + 32768);         // B kh0(1)
    vm8();                                                     // kh0(0) landed
    __builtin_amdgcn_s_barrier();

    #pragma unroll
    for (int t = 0; t < 8; ++t) {
        char* cur = smem + (t & 1) * 65536;
        char* nxt = smem + ((t + 1) & 1) * 65536;
        const char* curA = cur;
        const char* curB = cur + 32768;
        bf16x8 af[4], bf[4];

        // ================= phase 1: ks0, mi0-3 =================
        #pragma unroll
        for (int nj = 0; nj < 4; ++nj)
            bf[nj] = *(const bf16x8*)(curB + (wn * 4 + nj) * 1024 + lane * 16);
        #pragma unroll
        for (int mi = 0; mi < 4; ++mi)
            af[mi] = *(const bf16x8*)(curA + (wm * 8 + mi) * 1024 + lane * 16);
        if (t < 7) stage_half(zh, cbA + (t + 1) * 8 + 4, nxt + 16384);
        __builtin_amdgcn_s_barrier();
        lgkm0();
        __builtin_amdgcn_s_setprio(1);
        #pragma unroll
        for (int mi = 0; mi < 4; ++mi)
            #pragma unroll
            for (int nj = 0; nj < 4; ++nj)
                acc[mi][nj] = __builtin_amdgcn_mfma_f32_16x16x32_bf16(af[mi], bf[nj], acc[mi][nj], 0, 0, 0);
        __builtin_amdgcn_s_setprio(0);
        __builtin_amdgcn_s_barrier();

        // ================= phase 2: ks0, mi4-7 =================
        #pragma unroll
        for (int mi = 0; mi < 4; ++mi)
            af[mi] = *(const bf16x8*)(curA + (wm * 8 + 4 + mi) * 1024 + lane * 16);
        if (t < 7) stage_half(eh, cbB + (t + 1) * 8 + 4, nxt + 32768 + 16384);
        if (t < 7) vm8(); else vm0();      // guarantees kh1(t) for p3 reads
        __builtin_amdgcn_s_barrier();
        lgkm0();
        __builtin_amdgcn_s_setprio(1);
        #pragma unroll
        for (int mi = 0; mi < 4; ++mi)
            #pragma unroll
            for (int nj = 0; nj < 4; ++nj)
                acc[4 + mi][nj] = __builtin_amdgcn_mfma_f32_16x16x32_bf16(af[mi], bf[nj], acc[4 + mi][nj], 0, 0, 0);
        __builtin_amdgcn_s_setprio(0);
        __builtin_amdgcn_s_barrier();

        // ================= phase 3: ks1, mi0-3 =================
        #pragma unroll
        for (int nj = 0; nj < 4; ++nj)
            bf[nj] = *(const bf16x8*)(curB + 16384 + (wn * 4 + nj) * 1024 + lane * 16);
        #pragma unroll
        for (int mi = 0; mi < 4; ++mi)
            af[mi] = *(const bf16x8*)(curA + 16384 + (wm * 8 + mi) * 1024 + lane * 16);
        if (t < 6) stage_half(zh, cbA + (t + 2) * 8, cur);
        __builtin_amdgcn_s_barrier();
        lgkm0();
        __builtin_amdgcn_s_setprio(1);
        #pragma unroll
        for (int mi = 0; mi < 4; ++mi)
            #pragma unroll
            for (int nj = 0; nj < 4; ++nj)
                acc[mi][nj] = __builtin_amdgcn_mfma_f32_16x16x32_bf16(af[mi], bf[nj], acc[mi][nj], 0, 0, 0);
        __builtin_amdgcn_s_setprio(0);
        __builtin_amdgcn_s_barrier();

        // ================= phase 4: ks1, mi4-7 =================
        #pragma unroll
        for (int mi = 0; mi < 4; ++mi)
            af[mi] = *(const bf16x8*)(curA + 16384 + (wm * 8 + 4 + mi) * 1024 + lane * 16);
        if (t < 6) stage_half(eh, cbB + (t + 2) * 8, cur + 32768);
        if (t < 6) vm8(); else if (t == 6) vm4();   // guarantees kh0(t+1) for next p1
        __builtin_amdgcn_s_barrier();
        lgkm0();
        __builtin_amdgcn_s_setprio(1);
        #pragma unroll
        for (int mi = 0; mi < 4; ++mi)
            #pragma unroll
            for (int nj = 0; nj < 4; ++nj)
                acc[4 + mi][nj] = __builtin_amdgcn_mfma_f32_16x16x32_bf16(af[mi], bf[nj], acc[4 + mi][nj], 0, 0, 0);
        __builtin_amdgcn_s_setprio(0);
        __builtin_amdgcn_s_barrier();
    }

    // ---- selection epilogue: per token, top-2 over this wave's 64 cols ----
    // C/D layout (16x16x32): col = lane&15, row = (lane>>4)*4 + reg
    // u32 pack: score high bits | (col_local ^ 63)  (tie -> lower col wins;
    // truncation error <= 2e-4 absorbed by MARGIN; exact rescore follows)
    float inm[4]; unsigned ccode[4];
    #pragma unroll
    for (int nj = 0; nj < 4; ++nj) {
        int col = nj * 16 + (lane & 15);              // [0,64) within wave group
        ccode[nj] = (unsigned)(col ^ 63);
        inm[nj] = rsqrtf(norm_sq[f * NE + m0 + wn * 64 + col]);
    }

    #pragma unroll
    for (int mi = 0; mi < 8; ++mi) {
        #pragma unroll
        for (int r = 0; r < 4; ++r) {
            unsigned p1 = 0u, p2 = 0u;
            #pragma unroll
            for (int nj = 0; nj < 4; ++nj) {
                float w = acc[mi][nj][r] * inm[nj];
                unsigned pw = (ford(w) & 0xFFFFFFC0u) | ccode[nj];
                if (pw > p1) { p2 = p1; p1 = pw; }
                else if (pw > p2) p2 = pw;
            }
            // merge top-2 across the 16 contiguous lanes of this token row
            #pragma unroll
            for (int off = 8; off; off >>= 1) {
                unsigned q1 = __shfl_down(p1, off, 16);
                unsigned q2 = __shfl_down(p2, off, 16);
                if (q1 > p1) { unsigned tt = p1; p1 = q1; p2 = (tt > q2) ? tt : q2; }
                else         { p2 = (p2 > q1) ? p2 : q1; }
            }
            if ((lane & 15) == 0) {
                int u = t0 + wm * 128 + mi * 16 + (lane >> 4) * 4 + r;
                int b = u >> 8, n = u & 255;
                int gt = ((b * FCB + f) << 8) + n;   // global token id (b,f,n)
                int s = (blockIdx.x << 2) | wn;      // slot covers cols s*64..
                uint2 val; val.x = p1; val.y = p2;
                *(uint2*)(cand + ((size_t)gt << 7) + (s << 1)) = val;
            }
        }
    }
}

// ---- rescore + output epilogue: one wave per token (exact norms in-kernel) -
__global__ __launch_bounds__(256) void rescore_epilogue(
    const float* __restrict__ z, const float* __restrict__ emb,
    const unsigned int* __restrict__ cand,
    float* __restrict__ out, float* __restrict__ loss_tok)
{
    int t = blockIdx.x * 4 + (threadIdx.x >> 6);   // global token (b,f,n)
    int lane = threadIdx.x & 63;
    int n = t & 255;
    int f = (t >> 8) & 1;
    int b = t >> 9;
    const float* zrow = z + ((size_t)(b*NN + n))*EDIM + f*CC;
    float4 za = *(const float4*)(zrow + lane * 8);
    float4 zb = *(const float4*)(zrow + lane * 8 + 4);

    // 128 candidates: lane reads slot s == lane (2 packed u32)
    uint2 cc = *(const uint2*)(cand + ((size_t)t << 7) + (lane << 1));
    unsigned c1 = cc.x, c2 = cc.y;

    unsigned m1 = (c1 > c2) ? c1 : c2;
    #pragma unroll
    for (int off = 32; off; off >>= 1) {
        unsigned o = __shfl_xor(m1, off);
        if (o > m1) m1 = o;
    }
    float thr = unford(m1) - MARGIN;

    unsigned long long bestp = 0ull;
    #pragma unroll
    for (int rnd = 0; rnd < 2; ++rnd) {
        unsigned u = rnd ? c2 : c1;
        float v = unford(u);
        unsigned long long mask = __ballot(v > thr);
        while (mask) {
            int src = __ffsll((long long)mask) - 1;
            mask &= mask - 1;
            unsigned cu = __shfl(u, src);
            int idx = (src << 6) | ((int)(cu & 63u) ^ 63);   // proto index [0,4096)
            const float* er = emb + ((size_t)(f * NE + idx)) * CC;
            float4 ea = *(const float4*)(er + lane * 8);
            float4 eb = *(const float4*)(er + lane * 8 + 4);
            float d  = za.x*ea.x + za.y*ea.y + za.z*ea.z + za.w*ea.w
                     + zb.x*eb.x + zb.y*eb.y + zb.z*eb.z + zb.w*eb.w;
            float se = ea.x*ea.x + ea.y*ea.y + ea.z*ea.z + ea.w*ea.w
                     + eb.x*eb.x + eb.y*eb.y + eb.z*eb.z + eb.w*eb.w;
            #pragma unroll
            for (int off = 32; off; off >>= 1) {
                d  += __shfl_xor(d, off);
                se += __shfl_xor(se, off);
            }
            float vex = d / fmaxf(sqrtf(se), 1e-12f);        // exact score
            unsigned long long pex = ((unsigned long long)ford(vex) << 32)
                                   | (unsigned int)(~(unsigned int)idx);
            if (pex > bestp) bestp = pex;
        }
    }
    int idxb = (int)(~(unsigned int)bestp);    // exact argmax (tie -> lower idx)

    // ---- output: z_q gather (codebook-0 row, faithful quirk) + loss -------
    const float* er0 = emb + (size_t)idxb * CC;
    float4 ea = *(const float4*)(er0 + lane * 8);
    float4 eb = *(const float4*)(er0 + lane * 8 + 4);
    float se0 = ea.x*ea.x + ea.y*ea.y + ea.z*ea.z + ea.w*ea.w
              + eb.x*eb.x + eb.y*eb.y + eb.z*eb.z + eb.w*eb.w;
    #pragma unroll
    for (int off = 32; off; off >>= 1) se0 += __shfl_xor(se0, off);
    float inm0 = 1.0f / fmaxf(sqrtf(se0), 1e-12f);
    float* orow = out + ((size_t)(b*NN + n))*EDIM + f*CC;
    ea.x *= inm0; ea.y *= inm0; ea.z *= inm0; ea.w *= inm0;
    eb.x *= inm0; eb.y *= inm0; eb.z *= inm0; eb.w *= inm0;
    *(float4*)(orow + lane * 8) = ea;
    *(float4*)(orow + lane * 8 + 4) = eb;
    float s1 = za.x*za.x + za.y*za.y + za.z*za.z + za.w*za.w
             + zb.x*zb.x + zb.y*zb.y + zb.z*zb.z + zb.w*zb.w;
    float s2 = za.x*ea.x + za.y*ea.y + za.z*ea.z + za.w*ea.w
             + zb.x*eb.x + zb.y*eb.y + zb.z*eb.z + zb.w*eb.w;
    #pragma unroll
    for (int off = 32; off; off >>= 1) {
        s1 += __shfl_xor(s1, off);
        s2 += __shfl_xor(s2, off);
    }
    if (lane == 0) {
        float cosv = s2 / fmaxf(sqrtf(s1), 1e-12f);   // zn . z_q
        loss_tok[t] = 2.0f - 2.0f * cosv;
        out[OUT_IDX + t] = (float)idxb;               // indices read back as float
    }
}

// ---- final: sum per-token losses -> out[OUT_LOSS] --------------------------
__global__ __launch_bounds__(256) void loss_reduce(
    const float* __restrict__ loss_tok, float* __restrict__ out)
{
    int tid = threadIdx.x;
    float s = 0.f;
    #pragma unroll
    for (int h = 0; h < 32; ++h) s += loss_tok[h * 256 + tid];
    #pragma unroll
    for (int off = 32; off; off >>= 1) s += __shfl_down(s, off);
    __shared__ float part[4];
    if ((tid & 63) == 0) part[tid >> 6] = s;
    __syncthreads();
    if (tid == 0) {
        float t = part[0] + part[1] + part[2] + part[3];
        out[OUT_LOSS] = t * (1.25f / (float)OUT_LOSS);
    }
}

extern "C" void kernel_launch(void* const* d_in, const int* in_sizes, int n_in,
                              void* d_out, int out_size, void* d_ws, size_t ws_size,
                              hipStream_t stream) {
    const float* z   = (const float*)d_in[0];
    const float* emb = (const float*)d_in[1];
    float* out = (float*)d_out;

    char* ws = (char*)d_ws;
    float* norm_sq = (float*)ws;                                    // 32 KB
    unsigned int* cand = (unsigned int*)(ws + 32768);               // 4 MB
    float* loss_tok = (float*)(ws + 32768 + (size_t)4*1024*1024);   // 32 KB
    short* z_hi = (short*)(ws + 65536 + (size_t)4*1024*1024);       // 8 MB
    short* e_hi = z_hi + (size_t)FCB * NE * CC;                     // 8 MB
    // ws needed: ~20.1 MB

    hipMemsetAsync(norm_sq, 0, ROWS * sizeof(float), stream);
    pack_hi<<<4096, 256, 0, stream>>>(z, emb, z_hi, e_hi, norm_sq);
    gemm_sel<<<dim3(NE/256, NE/256, FCB), 512, 0, stream>>>(z_hi, e_hi, norm_sq, cand);
    rescore_epilogue<<<TOKENS/4, 256, 0, stream>>>(z, emb, cand, out, loss_tok);
    loss_reduce<<<1, 256, 0, stream>>>(loss_tok, out);
}